// Round 10
// baseline (373.768 us; speedup 1.0000x reference)
//
#include <hip/hip_runtime.h>
#include <math.h>

static inline size_t align256(size_t x) { return (x + 255) & ~(size_t)255; }

typedef __attribute__((ext_vector_type(8))) short bf16x8;
typedef __attribute__((ext_vector_type(4))) float f32x4;

// ---- bf16 helpers (fp32 accumulate everywhere; bf16 is storage only) ----
__device__ inline float bfLo(unsigned int u) {
  union { unsigned int i; float f; } v; v.i = u << 16; return v.f;
}
__device__ inline float bfHi(unsigned int u) {
  union { unsigned int i; float f; } v; v.i = u & 0xffff0000u; return v.f;
}
__device__ inline unsigned short f2bf(float f) {
  union { float f; unsigned int i; } v; v.f = f;
  unsigned int r = v.i + 0x7FFF + ((v.i >> 16) & 1);  // RNE
  return (unsigned short)(r >> 16);
}
__device__ inline unsigned int packbf(float lo, float hi) {
  return ((unsigned int)f2bf(hi) << 16) | f2bf(lo);
}

// ============ graph build: two-level LDS-privatized binning ============
// k_prep folded in: blocks also transpose W1/W2 to bf16 n-major.
__global__ __launch_bounds__(256) void k_coarse_count(const int* __restrict__ esrc,
                                                      const int* __restrict__ edst,
                                                      int E, int chunk, int NB, int G,
                                                      int* __restrict__ blkD,
                                                      int* __restrict__ blkS,
                                                      const float* __restrict__ W1,
                                                      const float* __restrict__ W2,
                                                      unsigned short* __restrict__ W1t,
                                                      unsigned short* __restrict__ W2t) {
  __shared__ int hD[512], hS[512];
  int blk = blockIdx.x, tid = threadIdx.x;
  int t = blk * 256 + tid;
  if (t < 128 * 128) {
    int nn = t >> 7, kk = t & 127;
    W1t[t] = f2bf(W1[kk * 128 + nn]);
  }
  if (t < 64 * 128) {
    int nn = t >> 7, kk = t & 127;
    W2t[t] = f2bf(W2[kk * 64 + nn]);
  }
  for (int i = tid; i < NB; i += 256) { hD[i] = 0; hS[i] = 0; }
  __syncthreads();
  int s0 = blk * chunk, s1 = min(E, s0 + chunk);
  for (int e = s0 + tid; e < s1; e += 256) {
    atomicAdd(&hD[edst[e] >> 8], 1);
    atomicAdd(&hS[esrc[e] >> 8], 1);
  }
  __syncthreads();
  for (int i = tid; i < NB; i += 256) {
    blkD[i * G + blk] = hD[i];
    blkS[i * G + blk] = hS[i];
  }
}

__global__ __launch_bounds__(256) void k_scan1(const int* __restrict__ in,
                                               int* __restrict__ out,
                                               int* __restrict__ bsums, int n) {
  __shared__ int s[256];
  int tid = threadIdx.x, gid = blockIdx.x * 256 + tid;
  int v = (gid < n) ? in[gid] : 0;
  s[tid] = v; __syncthreads();
  for (int o = 1; o < 256; o <<= 1) {
    int t = (tid >= o) ? s[tid - o] : 0;
    __syncthreads();
    s[tid] += t;
    __syncthreads();
  }
  if (gid < n) out[gid] = s[tid] - v;
  if (tid == 255) bsums[blockIdx.x] = s[255];
}

// grid = 2: block b scans bsums[b*nb .. b*nb+nb) independently (D half, S half)
__global__ __launch_bounds__(512) void k_scan2(int* __restrict__ bsums, int nb) {
  __shared__ int s[512];
  int tid = threadIdx.x;
  int* base = bsums + blockIdx.x * nb;
  int v = (tid < nb) ? base[tid] : 0;
  s[tid] = v; __syncthreads();
  for (int o = 1; o < 512; o <<= 1) {
    int t = (tid >= o) ? s[tid - o] : 0;
    __syncthreads();
    s[tid] += t;
    __syncthreads();
  }
  if (tid < nb) base[tid] = s[tid] - v;
}

// P3: packed scatter. pair = (src<<8)|(dst&255). scan3b folded: with G=256,
// full-scan value at sc[i*G+blk] = sc[i*G+blk] + bsums[i] (D) / bsums[NB+i] (S).
__global__ __launch_bounds__(256) void k_coarse_scatter(const int* __restrict__ esrc,
                                                        const int* __restrict__ edst,
                                                        int E, int chunk, int NB, int G,
                                                        const int* __restrict__ scD,
                                                        const int* __restrict__ scS,
                                                        const int* __restrict__ bsums,
                                                        unsigned int* __restrict__ pairs,
                                                        unsigned int* __restrict__ keys) {
  __shared__ int cD[512], cS[512];
  int blk = blockIdx.x, tid = threadIdx.x;
  for (int i = tid; i < NB; i += 256) {
    cD[i] = scD[i * G + blk] + bsums[i];
    cS[i] = scS[i * G + blk] + bsums[NB + i];
  }
  __syncthreads();
  int s0 = blk * chunk, s1 = min(E, s0 + chunk);
  for (int e = s0 + tid; e < s1; e += 256) {
    int s = esrc[e], d = edst[e];
    int pd = atomicAdd(&cD[d >> 8], 1);
    pairs[pd] = ((unsigned)s << 8) | ((unsigned)d & 255u);
    int ps = atomicAdd(&cS[s >> 8], 1);
    keys[ps] = (unsigned)s;
  }
}

// merged fine pass: blocks [0,NB) = dst buckets (csr build), [NB,2NB) = src buckets (normOut)
__global__ __launch_bounds__(256) void k_fine(const unsigned int* __restrict__ pairs,
                                              const unsigned int* __restrict__ keys,
                                              const int* __restrict__ scD,
                                              const int* __restrict__ scS,
                                              const int* __restrict__ bsums,
                                              int G, int E, int N, int NB,
                                              int* __restrict__ cntIn,
                                              float* __restrict__ normIn,
                                              int* __restrict__ offs,
                                              int* __restrict__ csr,
                                              float* __restrict__ normOut) {
  __shared__ int hist[256], scn[256], cur[256];
  int tid = threadIdx.x;
  if (blockIdx.x >= (unsigned)NB) {   // src half: degree -> normOut
    int b = blockIdx.x - NB;
    int bstart = scS[b * G] + bsums[NB + b];
    int bend = (b + 1 < NB) ? scS[(b + 1) * G] + bsums[NB + b + 1] : E;
    hist[tid] = 0;
    __syncthreads();
    for (int e = bstart + tid; e < bend; e += 256)
      atomicAdd(&hist[keys[e] & 255u], 1);
    __syncthreads();
    int node = b * 256 + tid;
    if (node < N) normOut[node] = rsqrtf((float)max(hist[tid], 1));
    return;
  }
  int b = blockIdx.x;
  int bstart = scD[b * G] + bsums[b];
  int bend = (b + 1 < NB) ? scD[(b + 1) * G] + bsums[b + 1] : E;
  hist[tid] = 0;
  __syncthreads();
  for (int e = bstart + tid; e < bend; e += 256)
    atomicAdd(&hist[pairs[e] & 255u], 1);
  __syncthreads();
  int v = hist[tid];
  scn[tid] = v;
  __syncthreads();
  for (int o = 1; o < 256; o <<= 1) {
    int t = (tid >= o) ? scn[tid - o] : 0;
    __syncthreads();
    scn[tid] += t;
    __syncthreads();
  }
  int excl = scn[tid] - v;
  cur[tid] = excl;
  int node = b * 256 + tid;
  if (node < N) {
    cntIn[node] = v;
    normIn[node] = rsqrtf((float)max(v, 1));
    offs[node] = bstart + excl;
  }
  __syncthreads();
  for (int e = bstart + tid; e < bend; e += 256) {
    unsigned int u = pairs[e];
    int p = bstart + atomicAdd(&cur[u & 255u], 1);
    csr[p] = (int)(u >> 8);
  }
}

// ---------------- MFMA GEMM: out[n x C](bf16) = diag(scale)*A[n x 128] @ W[128 x C] ----------------
template <int C, typename TA>
__global__ __launch_bounds__(256) void k_mgemm(const TA* __restrict__ A,
                                               const float* __restrict__ scale,
                                               const unsigned short* __restrict__ Wt,
                                               unsigned short* __restrict__ out, int n) {
  constexpr int KP = 136;
  constexpr int NCH = C / 16;
  __shared__ __align__(16) unsigned short Al[64 * KP];
  __shared__ __align__(16) unsigned short Wl[C * KP];
  int tid = threadIdx.x;
  int r0 = blockIdx.x * 64;

  {
    const uint4* Wg = (const uint4*)Wt;
    uint4* Wd = (uint4*)Wl;
    for (int idx = tid; idx < C * 16; idx += 256) {
      int row = idx >> 4, seg = idx & 15;
      Wd[row * 17 + seg] = Wg[idx];
    }
  }
  {
    int seg = tid & 7;
    for (int it = 0; it < 2; ++it) {
      int row = (tid >> 3) + it * 32;
      int g = r0 + row;
      float v[16];
      if (g < n) {
        float sc = scale[g];
        if constexpr (sizeof(TA) == 4) {
          const float4* Ag = (const float4*)((const float*)A + (size_t)g * 128);
#pragma unroll
          for (int j = 0; j < 4; ++j) {
            float4 f = Ag[seg * 4 + j];
            v[j * 4 + 0] = f.x * sc; v[j * 4 + 1] = f.y * sc;
            v[j * 4 + 2] = f.z * sc; v[j * 4 + 3] = f.w * sc;
          }
        } else {
          const uint4* Ag = (const uint4*)((const unsigned short*)A + (size_t)g * 128);
#pragma unroll
          for (int j = 0; j < 2; ++j) {
            uint4 u = Ag[seg * 2 + j];
            v[j * 8 + 0] = bfLo(u.x) * sc; v[j * 8 + 1] = bfHi(u.x) * sc;
            v[j * 8 + 2] = bfLo(u.y) * sc; v[j * 8 + 3] = bfHi(u.y) * sc;
            v[j * 8 + 4] = bfLo(u.z) * sc; v[j * 8 + 5] = bfHi(u.z) * sc;
            v[j * 8 + 6] = bfLo(u.w) * sc; v[j * 8 + 7] = bfHi(u.w) * sc;
          }
        }
      } else {
#pragma unroll
        for (int j = 0; j < 16; ++j) v[j] = 0.f;
      }
      uint4* dst = (uint4*)(Al + row * KP + seg * 16);
      dst[0] = make_uint4(packbf(v[0], v[1]), packbf(v[2], v[3]),
                          packbf(v[4], v[5]), packbf(v[6], v[7]));
      dst[1] = make_uint4(packbf(v[8], v[9]), packbf(v[10], v[11]),
                          packbf(v[12], v[13]), packbf(v[14], v[15]));
    }
  }
  __syncthreads();

  int lane = tid & 63;
  int w = tid >> 6;
  int quad = lane >> 4, m16 = lane & 15;
  f32x4 acc[NCH];
#pragma unroll
  for (int c = 0; c < NCH; ++c) acc[c] = (f32x4){0.f, 0.f, 0.f, 0.f};

#pragma unroll
  for (int kc = 0; kc < 4; ++kc) {
    int ko = kc * 32 + quad * 8;
    bf16x8 a = *(const bf16x8*)(Al + (w * 16 + m16) * KP + ko);
#pragma unroll
    for (int c = 0; c < NCH; ++c) {
      bf16x8 b = *(const bf16x8*)(Wl + (c * 16 + m16) * KP + ko);
      acc[c] = __builtin_amdgcn_mfma_f32_16x16x32_bf16(a, b, acc[c], 0, 0, 0);
    }
  }

#pragma unroll
  for (int c = 0; c < NCH; ++c)
#pragma unroll
    for (int r = 0; r < 4; ++r) {
      int g = r0 + w * 16 + quad * 4 + r;
      if (g < n) out[(size_t)g * C + c * 16 + m16] = f2bf(acc[c][r]);
    }
}

// ---------------- layer-1 aggregation (R8 structure, deeper pipeline) ----------------
// R9 post-mortem: XCD column-split regressed (2x per-edge issue work for -12%
// bytes). Back to full-row gather: 4 edges x 16 lanes x uint4, but 8 row-loads
// in flight per lane (e+=32) to hide L2-miss latency.
__global__ __launch_bounds__(256) void k_agg128_relu(const unsigned short* __restrict__ X,
                                                     const int* __restrict__ csr,
                                                     const int* __restrict__ offs,
                                                     const int* __restrict__ cnt,
                                                     const float* __restrict__ norm,
                                                     const float* __restrict__ bias,
                                                     unsigned short* __restrict__ H, int n) {
  int wid = blockIdx.x * 4 + (threadIdx.x >> 6);
  if (wid >= n) return;
  int lane = threadIdx.x & 63;
  int sub = lane & 15;          // 16B segment within the 256B row
  int grp = lane >> 4;          // 4 edges concurrent
  int start = offs[wid], m = cnt[wid];
  const int* p = csr + start;
  const uint4* Xv = (const uint4*)X;  // row stride 16 uint4
  float a[8] = {0.f, 0.f, 0.f, 0.f, 0.f, 0.f, 0.f, 0.f};
  for (int c0 = 0; c0 < m; c0 += 64) {
    int take = min(64, m - c0);
    int iv = p[c0 + ((lane < take) ? lane : take - 1)];   // one coalesced load
    int e = 0;
    for (; e + 32 <= take; e += 32) {
      uint4 uu[8];
#pragma unroll
      for (int j = 0; j < 8; ++j) {
        int ss = __shfl(iv, e + j * 4 + grp);
        uu[j] = Xv[(size_t)ss * 16 + sub];
      }
#pragma unroll
      for (int j = 0; j < 8; ++j) {
        a[0] += bfLo(uu[j].x); a[1] += bfHi(uu[j].x);
        a[2] += bfLo(uu[j].y); a[3] += bfHi(uu[j].y);
        a[4] += bfLo(uu[j].z); a[5] += bfHi(uu[j].z);
        a[6] += bfLo(uu[j].w); a[7] += bfHi(uu[j].w);
      }
    }
    for (; e + 4 <= take; e += 4) {
      int ss = __shfl(iv, e + grp);
      uint4 u = Xv[(size_t)ss * 16 + sub];
      a[0] += bfLo(u.x); a[1] += bfHi(u.x);
      a[2] += bfLo(u.y); a[3] += bfHi(u.y);
      a[4] += bfLo(u.z); a[5] += bfHi(u.z);
      a[6] += bfLo(u.w); a[7] += bfHi(u.w);
    }
    int r = take - e;
    if (r > 0) {
      int ss = __shfl(iv, min(e + grp, take - 1));
      uint4 u = Xv[(size_t)ss * 16 + sub];
      if (grp < r) {
        a[0] += bfLo(u.x); a[1] += bfHi(u.x);
        a[2] += bfLo(u.y); a[3] += bfHi(u.y);
        a[4] += bfLo(u.z); a[5] += bfHi(u.z);
        a[6] += bfLo(u.w); a[7] += bfHi(u.w);
      }
    }
  }
#pragma unroll
  for (int k = 0; k < 8; ++k) {
    a[k] += __shfl_xor(a[k], 16);
    a[k] += __shfl_xor(a[k], 32);
  }
  float nm = norm[wid];
  const float4* bv = (const float4*)bias;     // cols sub*8 .. sub*8+7
  float4 b0 = bv[sub * 2], b1 = bv[sub * 2 + 1];
  if (grp == 0) {
    float o0 = fmaxf(a[0] * nm + b0.x, 0.f);
    float o1 = fmaxf(a[1] * nm + b0.y, 0.f);
    float o2 = fmaxf(a[2] * nm + b0.z, 0.f);
    float o3 = fmaxf(a[3] * nm + b0.w, 0.f);
    float o4 = fmaxf(a[4] * nm + b1.x, 0.f);
    float o5 = fmaxf(a[5] * nm + b1.y, 0.f);
    float o6 = fmaxf(a[6] * nm + b1.z, 0.f);
    float o7 = fmaxf(a[7] * nm + b1.w, 0.f);
    uint4 o = make_uint4(packbf(o0, o1), packbf(o2, o3),
                         packbf(o4, o5), packbf(o6, o7));
    ((uint4*)H)[(size_t)wid * 16 + sub] = o;
  }
}

// layer-2 aggregation: 8 edges x 8 lanes x uint4; full-chunk unroll = 8 loads in flight
__global__ __launch_bounds__(256) void k_agg64(const unsigned short* __restrict__ X,
                                               const int* __restrict__ csr,
                                               const int* __restrict__ offs,
                                               const int* __restrict__ cnt,
                                               const float* __restrict__ norm,
                                               const float* __restrict__ bias,
                                               unsigned short* __restrict__ H, int n) {
  int wid = blockIdx.x * 4 + (threadIdx.x >> 6);
  if (wid >= n) return;
  int lane = threadIdx.x & 63;
  int sub = lane & 7;           // 16B segment within the 128B row
  int grp = lane >> 3;          // 8 edges concurrent
  int start = offs[wid], m = cnt[wid];
  const int* p = csr + start;
  const uint4* Xv = (const uint4*)X;  // row stride 8 uint4
  float a[8] = {0.f, 0.f, 0.f, 0.f, 0.f, 0.f, 0.f, 0.f};
  for (int c0 = 0; c0 < m; c0 += 64) {
    int take = min(64, m - c0);
    int iv = p[c0 + ((lane < take) ? lane : take - 1)];
    int e = 0;
    for (; e + 64 <= take; e += 64) {
      uint4 uu[8];
#pragma unroll
      for (int j = 0; j < 8; ++j) {
        int ss = __shfl(iv, e + j * 8 + grp);
        uu[j] = Xv[(size_t)ss * 8 + sub];
      }
#pragma unroll
      for (int j = 0; j < 8; ++j) {
        a[0] += bfLo(uu[j].x); a[1] += bfHi(uu[j].x);
        a[2] += bfLo(uu[j].y); a[3] += bfHi(uu[j].y);
        a[4] += bfLo(uu[j].z); a[5] += bfHi(uu[j].z);
        a[6] += bfLo(uu[j].w); a[7] += bfHi(uu[j].w);
      }
    }
    for (; e + 8 <= take; e += 8) {
      int ss = __shfl(iv, e + grp);
      uint4 u = Xv[(size_t)ss * 8 + sub];
      a[0] += bfLo(u.x); a[1] += bfHi(u.x);
      a[2] += bfLo(u.y); a[3] += bfHi(u.y);
      a[4] += bfLo(u.z); a[5] += bfHi(u.z);
      a[6] += bfLo(u.w); a[7] += bfHi(u.w);
    }
    int r = take - e;
    if (r > 0) {
      int ss = __shfl(iv, min(e + grp, take - 1));
      uint4 u = Xv[(size_t)ss * 8 + sub];
      if (grp < r) {
        a[0] += bfLo(u.x); a[1] += bfHi(u.x);
        a[2] += bfLo(u.y); a[3] += bfHi(u.y);
        a[4] += bfLo(u.z); a[5] += bfHi(u.z);
        a[6] += bfLo(u.w); a[7] += bfHi(u.w);
      }
    }
  }
#pragma unroll
  for (int k = 0; k < 8; ++k) {
    a[k] += __shfl_xor(a[k], 8);
    a[k] += __shfl_xor(a[k], 16);
    a[k] += __shfl_xor(a[k], 32);
  }
  float nm = norm[wid];
  const float4* bv = (const float4*)bias;
  float4 b0 = bv[sub * 2], b1 = bv[sub * 2 + 1];
  if (grp == 0) {
    uint4 o = make_uint4(packbf(a[0] * nm + b0.x, a[1] * nm + b0.y),
                         packbf(a[2] * nm + b0.z, a[3] * nm + b0.w),
                         packbf(a[4] * nm + b1.x, a[5] * nm + b1.y),
                         packbf(a[6] * nm + b1.z, a[7] * nm + b1.w));
    ((uint4*)H)[(size_t)wid * 8 + sub] = o;
  }
}

// ---------------- edge scoring: 8 lanes/query, 2 queries/thread (4 loads in flight) ----------------
__global__ __launch_bounds__(256) void k_score(const unsigned short* __restrict__ H,
                                               const int* __restrict__ qs,
                                               const int* __restrict__ qd,
                                               float* __restrict__ out, int q, int qStride) {
  int t = blockIdx.x * 256 + threadIdx.x;
  int sub = t & 7;
  int q0 = t >> 3;
  int q1 = q0 + qStride;
  const uint4* Hv = (const uint4*)H;   // row stride 8 uint4
  float p0 = 0.f, p1 = 0.f;
  if (q0 < q) {
    uint4 a = Hv[(size_t)qs[q0] * 8 + sub];
    uint4 b = Hv[(size_t)qd[q0] * 8 + sub];
    uint4 c, d;
    bool has1 = (q1 < q);
    if (has1) {
      c = Hv[(size_t)qs[q1] * 8 + sub];
      d = Hv[(size_t)qd[q1] * 8 + sub];
    }
    p0 = bfLo(a.x) * bfLo(b.x) + bfHi(a.x) * bfHi(b.x) +
         bfLo(a.y) * bfLo(b.y) + bfHi(a.y) * bfHi(b.y) +
         bfLo(a.z) * bfLo(b.z) + bfHi(a.z) * bfHi(b.z) +
         bfLo(a.w) * bfLo(b.w) + bfHi(a.w) * bfHi(b.w);
    if (has1)
      p1 = bfLo(c.x) * bfLo(d.x) + bfHi(c.x) * bfHi(d.x) +
           bfLo(c.y) * bfLo(d.y) + bfHi(c.y) * bfHi(d.y) +
           bfLo(c.z) * bfLo(d.z) + bfHi(c.z) * bfHi(d.z) +
           bfLo(c.w) * bfLo(d.w) + bfHi(c.w) * bfHi(d.w);
  }
  p0 += __shfl_xor(p0, 1); p1 += __shfl_xor(p1, 1);
  p0 += __shfl_xor(p0, 2); p1 += __shfl_xor(p1, 2);
  p0 += __shfl_xor(p0, 4); p1 += __shfl_xor(p1, 4);
  if (sub == 0 && q0 < q) {
    out[q0] = 1.f / (1.f + expf(-p0));
    if (q1 < q) out[q1] = 1.f / (1.f + expf(-p1));
  }
}

extern "C" void kernel_launch(void* const* d_in, const int* in_sizes, int n_in,
                              void* d_out, int out_size, void* d_ws, size_t ws_size,
                              hipStream_t stream) {
  const float* feat = (const float*)d_in[0];
  const int* esrc   = (const int*)d_in[1];
  const int* edst   = (const int*)d_in[2];
  const int* qsrc   = (const int*)d_in[3];
  const int* qdst   = (const int*)d_in[4];
  const float* W1   = (const float*)d_in[5];
  const float* b1   = (const float*)d_in[6];
  const float* W2   = (const float*)d_in[7];
  const float* b2   = (const float*)d_in[8];
  float* out = (float*)d_out;

  const int N = in_sizes[0] / 128;
  const int E = in_sizes[1];
  const int Q = in_sizes[3];

  const int G = 256;
  const int NB = (N + 255) >> 8;
  const int chunk = (E + G - 1) / G;
  const int lenS = NB * G;
  const int gScan = lenS / 256;        // == NB, blocks per half

  char* w = (char*)d_ws;
  size_t o = 0;
  unsigned short* X1 = (unsigned short*)(w + o); o += align256((size_t)N * 128 * 2);
  unsigned short* X2 = (unsigned short*)(w + o); o += align256((size_t)N * 64 * 2);
  unsigned short* H2 = (unsigned short*)(w + o); o += align256((size_t)N * 64 * 2);
  int* cntIn = (int*)(w + o);       o += align256((size_t)N * 4);
  float* normOut = (float*)(w + o); o += align256((size_t)N * 4);
  float* normIn = (float*)(w + o);  o += align256((size_t)N * 4);
  int* offs = (int*)(w + o);        o += align256((size_t)N * 4);
  int* blk = (int*)(w + o);         o += align256((size_t)lenS * 8);   // D half + S half
  int* sc = (int*)(w + o);          o += align256((size_t)lenS * 8);   // D half + S half
  int* bsums = (int*)(w + o);       o += align256((size_t)8192);
  unsigned short* W1t = (unsigned short*)(w + o); o += align256((size_t)128 * 128 * 2);
  unsigned short* W2t = (unsigned short*)(w + o); o += align256((size_t)64 * 128 * 2);
  unsigned int* pairs = (unsigned int*)(w + o); o += align256((size_t)E * 4);
  unsigned int* keys = (unsigned int*)(w + o); o += align256((size_t)E * 4);
  int* csr = (int*)(w + o);         o += align256((size_t)E * 4);

  int* blkD = blk;        int* blkS = blk + lenS;
  int* scD = sc;          int* scS = sc + lenS;

  // graph build (no global atomics); prep folded into count, scan3 folded into consumers
  k_coarse_count<<<G, 256, 0, stream>>>(esrc, edst, E, chunk, NB, G, blkD, blkS,
                                        W1, W2, W1t, W2t);
  k_scan1<<<2 * gScan, 256, 0, stream>>>(blk, sc, bsums, 2 * lenS);
  k_scan2<<<2, 512, 0, stream>>>(bsums, gScan);
  k_coarse_scatter<<<G, 256, 0, stream>>>(esrc, edst, E, chunk, NB, G, scD, scS,
                                          bsums, pairs, keys);
  k_fine<<<2 * NB, 256, 0, stream>>>(pairs, keys, scD, scS, bsums, G, E, N, NB,
                                     cntIn, normIn, offs, csr, normOut);

  const int gRows = (N + 63) / 64;
  // layer 1: X1 = (feat*normOut)@W1 ; H1 = relu(agg(X1)*normIn + b1)    [bf16]
  k_mgemm<128, float><<<gRows, 256, 0, stream>>>(feat, normOut, W1t, X1, N);
  k_agg128_relu<<<(N + 3) / 4, 256, 0, stream>>>(X1, csr, offs, cntIn, normIn, b1, X2, N);
  // layer 2: X2b = (H1*normOut)@W2 ; H2 = agg(X2b)*normIn + b2          [bf16]
  k_mgemm<64, unsigned short><<<gRows, 256, 0, stream>>>(X2, normOut, W2t, X1, N);
  k_agg64<<<(N + 3) / 4, 256, 0, stream>>>(X1, csr, offs, cntIn, normIn, b2, H2, N);
  // scoring: 2 queries per thread
  const int qHalf = (Q + 1) / 2;
  k_score<<<((qHalf * 8) + 255) / 256, 256, 0, stream>>>(H2, qsrc, qdst, out, Q, qHalf);
}

// Round 11
// 324.551 us; speedup vs baseline: 1.1516x; 1.1516x over previous
//
#include <hip/hip_runtime.h>
#include <math.h>

static inline size_t align256(size_t x) { return (x + 255) & ~(size_t)255; }

typedef __attribute__((ext_vector_type(8))) short bf16x8;
typedef __attribute__((ext_vector_type(4))) float f32x4;

// ---- bf16 helpers (fp32 accumulate everywhere; bf16 is storage only) ----
__device__ inline float bfLo(unsigned int u) {
  union { unsigned int i; float f; } v; v.i = u << 16; return v.f;
}
__device__ inline float bfHi(unsigned int u) {
  union { unsigned int i; float f; } v; v.i = u & 0xffff0000u; return v.f;
}
__device__ inline unsigned short f2bf(float f) {
  union { float f; unsigned int i; } v; v.f = f;
  unsigned int r = v.i + 0x7FFF + ((v.i >> 16) & 1);  // RNE
  return (unsigned short)(r >> 16);
}
__device__ inline unsigned int packbf(float lo, float hi) {
  return ((unsigned int)f2bf(hi) << 16) | f2bf(lo);
}

// ============ graph build: two-level LDS-privatized binning ============
// k_prep folded in: blocks also transpose W1/W2 to bf16 n-major.
__global__ __launch_bounds__(256) void k_coarse_count(const int* __restrict__ esrc,
                                                      const int* __restrict__ edst,
                                                      int E, int chunk, int NB, int G,
                                                      int* __restrict__ blkD,
                                                      int* __restrict__ blkS,
                                                      const float* __restrict__ W1,
                                                      const float* __restrict__ W2,
                                                      unsigned short* __restrict__ W1t,
                                                      unsigned short* __restrict__ W2t) {
  __shared__ int hD[512], hS[512];
  int blk = blockIdx.x, tid = threadIdx.x;
  int t = blk * 256 + tid;
  if (t < 128 * 128) {
    int nn = t >> 7, kk = t & 127;
    W1t[t] = f2bf(W1[kk * 128 + nn]);
  }
  if (t < 64 * 128) {
    int nn = t >> 7, kk = t & 127;
    W2t[t] = f2bf(W2[kk * 64 + nn]);
  }
  for (int i = tid; i < NB; i += 256) { hD[i] = 0; hS[i] = 0; }
  __syncthreads();
  int s0 = blk * chunk, s1 = min(E, s0 + chunk);
  for (int e = s0 + tid; e < s1; e += 256) {
    atomicAdd(&hD[edst[e] >> 8], 1);
    atomicAdd(&hS[esrc[e] >> 8], 1);
  }
  __syncthreads();
  for (int i = tid; i < NB; i += 256) {
    blkD[i * G + blk] = hD[i];
    blkS[i * G + blk] = hS[i];
  }
}

__global__ __launch_bounds__(256) void k_scan1(const int* __restrict__ in,
                                               int* __restrict__ out,
                                               int* __restrict__ bsums, int n) {
  __shared__ int s[256];
  int tid = threadIdx.x, gid = blockIdx.x * 256 + tid;
  int v = (gid < n) ? in[gid] : 0;
  s[tid] = v; __syncthreads();
  for (int o = 1; o < 256; o <<= 1) {
    int t = (tid >= o) ? s[tid - o] : 0;
    __syncthreads();
    s[tid] += t;
    __syncthreads();
  }
  if (gid < n) out[gid] = s[tid] - v;
  if (tid == 255) bsums[blockIdx.x] = s[255];
}

// grid = 2: block b scans bsums[b*nb .. b*nb+nb) independently (D half, S half)
__global__ __launch_bounds__(512) void k_scan2(int* __restrict__ bsums, int nb) {
  __shared__ int s[512];
  int tid = threadIdx.x;
  int* base = bsums + blockIdx.x * nb;
  int v = (tid < nb) ? base[tid] : 0;
  s[tid] = v; __syncthreads();
  for (int o = 1; o < 512; o <<= 1) {
    int t = (tid >= o) ? s[tid - o] : 0;
    __syncthreads();
    s[tid] += t;
    __syncthreads();
  }
  if (tid < nb) base[tid] = s[tid] - v;
}

// P3: packed scatter. pair = (src<<8)|(dst&255). scan3b folded: with G=256,
// full-scan value at sc[i*G+blk] = sc[i*G+blk] + bsums[i] (D) / bsums[NB+i] (S).
__global__ __launch_bounds__(256) void k_coarse_scatter(const int* __restrict__ esrc,
                                                        const int* __restrict__ edst,
                                                        int E, int chunk, int NB, int G,
                                                        const int* __restrict__ scD,
                                                        const int* __restrict__ scS,
                                                        const int* __restrict__ bsums,
                                                        unsigned int* __restrict__ pairs,
                                                        unsigned int* __restrict__ keys) {
  __shared__ int cD[512], cS[512];
  int blk = blockIdx.x, tid = threadIdx.x;
  for (int i = tid; i < NB; i += 256) {
    cD[i] = scD[i * G + blk] + bsums[i];
    cS[i] = scS[i * G + blk] + bsums[NB + i];
  }
  __syncthreads();
  int s0 = blk * chunk, s1 = min(E, s0 + chunk);
  for (int e = s0 + tid; e < s1; e += 256) {
    int s = esrc[e], d = edst[e];
    int pd = atomicAdd(&cD[d >> 8], 1);
    pairs[pd] = ((unsigned)s << 8) | ((unsigned)d & 255u);
    int ps = atomicAdd(&cS[s >> 8], 1);
    keys[ps] = (unsigned)s;
  }
}

// merged fine pass: blocks [0,NB) = dst buckets (csr build), [NB,2NB) = src buckets (normOut)
__global__ __launch_bounds__(256) void k_fine(const unsigned int* __restrict__ pairs,
                                              const unsigned int* __restrict__ keys,
                                              const int* __restrict__ scD,
                                              const int* __restrict__ scS,
                                              const int* __restrict__ bsums,
                                              int G, int E, int N, int NB,
                                              int* __restrict__ cntIn,
                                              float* __restrict__ normIn,
                                              int* __restrict__ offs,
                                              int* __restrict__ csr,
                                              float* __restrict__ normOut) {
  __shared__ int hist[256], scn[256], cur[256];
  int tid = threadIdx.x;
  if (blockIdx.x >= (unsigned)NB) {   // src half: degree -> normOut
    int b = blockIdx.x - NB;
    int bstart = scS[b * G] + bsums[NB + b];
    int bend = (b + 1 < NB) ? scS[(b + 1) * G] + bsums[NB + b + 1] : E;
    hist[tid] = 0;
    __syncthreads();
    for (int e = bstart + tid; e < bend; e += 256)
      atomicAdd(&hist[keys[e] & 255u], 1);
    __syncthreads();
    int node = b * 256 + tid;
    if (node < N) normOut[node] = rsqrtf((float)max(hist[tid], 1));
    return;
  }
  int b = blockIdx.x;
  int bstart = scD[b * G] + bsums[b];
  int bend = (b + 1 < NB) ? scD[(b + 1) * G] + bsums[b + 1] : E;
  hist[tid] = 0;
  __syncthreads();
  for (int e = bstart + tid; e < bend; e += 256)
    atomicAdd(&hist[pairs[e] & 255u], 1);
  __syncthreads();
  int v = hist[tid];
  scn[tid] = v;
  __syncthreads();
  for (int o = 1; o < 256; o <<= 1) {
    int t = (tid >= o) ? scn[tid - o] : 0;
    __syncthreads();
    scn[tid] += t;
    __syncthreads();
  }
  int excl = scn[tid] - v;
  cur[tid] = excl;
  int node = b * 256 + tid;
  if (node < N) {
    cntIn[node] = v;
    normIn[node] = rsqrtf((float)max(v, 1));
    offs[node] = bstart + excl;
  }
  __syncthreads();
  for (int e = bstart + tid; e < bend; e += 256) {
    unsigned int u = pairs[e];
    int p = bstart + atomicAdd(&cur[u & 255u], 1);
    csr[p] = (int)(u >> 8);
  }
}

// ---------------- MFMA GEMM: out[n x C](bf16) = diag(scale)*A[n x 128] @ W[128 x C] ----------------
template <int C, typename TA>
__global__ __launch_bounds__(256) void k_mgemm(const TA* __restrict__ A,
                                               const float* __restrict__ scale,
                                               const unsigned short* __restrict__ Wt,
                                               unsigned short* __restrict__ out, int n) {
  constexpr int KP = 136;
  constexpr int NCH = C / 16;
  __shared__ __align__(16) unsigned short Al[64 * KP];
  __shared__ __align__(16) unsigned short Wl[C * KP];
  int tid = threadIdx.x;
  int r0 = blockIdx.x * 64;

  {
    const uint4* Wg = (const uint4*)Wt;
    uint4* Wd = (uint4*)Wl;
    for (int idx = tid; idx < C * 16; idx += 256) {
      int row = idx >> 4, seg = idx & 15;
      Wd[row * 17 + seg] = Wg[idx];
    }
  }
  {
    int seg = tid & 7;
    for (int it = 0; it < 2; ++it) {
      int row = (tid >> 3) + it * 32;
      int g = r0 + row;
      float v[16];
      if (g < n) {
        float sc = scale[g];
        if constexpr (sizeof(TA) == 4) {
          const float4* Ag = (const float4*)((const float*)A + (size_t)g * 128);
#pragma unroll
          for (int j = 0; j < 4; ++j) {
            float4 f = Ag[seg * 4 + j];
            v[j * 4 + 0] = f.x * sc; v[j * 4 + 1] = f.y * sc;
            v[j * 4 + 2] = f.z * sc; v[j * 4 + 3] = f.w * sc;
          }
        } else {
          const uint4* Ag = (const uint4*)((const unsigned short*)A + (size_t)g * 128);
#pragma unroll
          for (int j = 0; j < 2; ++j) {
            uint4 u = Ag[seg * 2 + j];
            v[j * 8 + 0] = bfLo(u.x) * sc; v[j * 8 + 1] = bfHi(u.x) * sc;
            v[j * 8 + 2] = bfLo(u.y) * sc; v[j * 8 + 3] = bfHi(u.y) * sc;
            v[j * 8 + 4] = bfLo(u.z) * sc; v[j * 8 + 5] = bfHi(u.z) * sc;
            v[j * 8 + 6] = bfLo(u.w) * sc; v[j * 8 + 7] = bfHi(u.w) * sc;
          }
        }
      } else {
#pragma unroll
        for (int j = 0; j < 16; ++j) v[j] = 0.f;
      }
      uint4* dst = (uint4*)(Al + row * KP + seg * 16);
      dst[0] = make_uint4(packbf(v[0], v[1]), packbf(v[2], v[3]),
                          packbf(v[4], v[5]), packbf(v[6], v[7]));
      dst[1] = make_uint4(packbf(v[8], v[9]), packbf(v[10], v[11]),
                          packbf(v[12], v[13]), packbf(v[14], v[15]));
    }
  }
  __syncthreads();

  int lane = tid & 63;
  int w = tid >> 6;
  int quad = lane >> 4, m16 = lane & 15;
  f32x4 acc[NCH];
#pragma unroll
  for (int c = 0; c < NCH; ++c) acc[c] = (f32x4){0.f, 0.f, 0.f, 0.f};

#pragma unroll
  for (int kc = 0; kc < 4; ++kc) {
    int ko = kc * 32 + quad * 8;
    bf16x8 a = *(const bf16x8*)(Al + (w * 16 + m16) * KP + ko);
#pragma unroll
    for (int c = 0; c < NCH; ++c) {
      bf16x8 b = *(const bf16x8*)(Wl + (c * 16 + m16) * KP + ko);
      acc[c] = __builtin_amdgcn_mfma_f32_16x16x32_bf16(a, b, acc[c], 0, 0, 0);
    }
  }

#pragma unroll
  for (int c = 0; c < NCH; ++c)
#pragma unroll
    for (int r = 0; r < 4; ++r) {
      int g = r0 + w * 16 + quad * 4 + r;
      if (g < n) out[(size_t)g * C + c * 16 + m16] = f2bf(acc[c][r]);
    }
}

// ---------------- layer-1 aggregation (R8 champion config) ----------------
// R9 (column-split: -12% bytes, 2x issue) and R10 (8-deep pipeline: 48 VGPR,
// occupancy 72->46%) both regressed vs this: 4 edges x 16 lanes x uint4,
// 4 row-loads in flight, 32 VGPR, ~72% occupancy. Outstanding-load product
// (waves/CU x loads-in-flight) is maximized here.
__global__ __launch_bounds__(256) void k_agg128_relu(const unsigned short* __restrict__ X,
                                                     const int* __restrict__ csr,
                                                     const int* __restrict__ offs,
                                                     const int* __restrict__ cnt,
                                                     const float* __restrict__ norm,
                                                     const float* __restrict__ bias,
                                                     unsigned short* __restrict__ H, int n) {
  int wid = blockIdx.x * 4 + (threadIdx.x >> 6);
  if (wid >= n) return;
  int lane = threadIdx.x & 63;
  int sub = lane & 15;          // 16B segment within the 256B row
  int grp = lane >> 4;          // 4 edges concurrent
  int start = offs[wid], m = cnt[wid];
  const int* p = csr + start;
  const uint4* Xv = (const uint4*)X;  // row stride 16 uint4
  float a[8] = {0.f, 0.f, 0.f, 0.f, 0.f, 0.f, 0.f, 0.f};
  for (int c0 = 0; c0 < m; c0 += 64) {
    int take = min(64, m - c0);
    int iv = p[c0 + ((lane < take) ? lane : take - 1)];   // one coalesced load
    int e = 0;
    for (; e + 16 <= take; e += 16) {
      uint4 uu[4];
#pragma unroll
      for (int j = 0; j < 4; ++j) {
        int ss = __shfl(iv, e + j * 4 + grp);
        uu[j] = Xv[(size_t)ss * 16 + sub];
      }
#pragma unroll
      for (int j = 0; j < 4; ++j) {
        a[0] += bfLo(uu[j].x); a[1] += bfHi(uu[j].x);
        a[2] += bfLo(uu[j].y); a[3] += bfHi(uu[j].y);
        a[4] += bfLo(uu[j].z); a[5] += bfHi(uu[j].z);
        a[6] += bfLo(uu[j].w); a[7] += bfHi(uu[j].w);
      }
    }
    for (; e + 4 <= take; e += 4) {
      int ss = __shfl(iv, e + grp);
      uint4 u = Xv[(size_t)ss * 16 + sub];
      a[0] += bfLo(u.x); a[1] += bfHi(u.x);
      a[2] += bfLo(u.y); a[3] += bfHi(u.y);
      a[4] += bfLo(u.z); a[5] += bfHi(u.z);
      a[6] += bfLo(u.w); a[7] += bfHi(u.w);
    }
    int r = take - e;
    if (r > 0) {
      int ss = __shfl(iv, min(e + grp, take - 1));
      uint4 u = Xv[(size_t)ss * 16 + sub];
      if (grp < r) {
        a[0] += bfLo(u.x); a[1] += bfHi(u.x);
        a[2] += bfLo(u.y); a[3] += bfHi(u.y);
        a[4] += bfLo(u.z); a[5] += bfHi(u.z);
        a[6] += bfLo(u.w); a[7] += bfHi(u.w);
      }
    }
  }
#pragma unroll
  for (int k = 0; k < 8; ++k) {
    a[k] += __shfl_xor(a[k], 16);
    a[k] += __shfl_xor(a[k], 32);
  }
  float nm = norm[wid];
  const float4* bv = (const float4*)bias;     // cols sub*8 .. sub*8+7
  float4 b0 = bv[sub * 2], b1 = bv[sub * 2 + 1];
  if (grp == 0) {
    float o0 = fmaxf(a[0] * nm + b0.x, 0.f);
    float o1 = fmaxf(a[1] * nm + b0.y, 0.f);
    float o2 = fmaxf(a[2] * nm + b0.z, 0.f);
    float o3 = fmaxf(a[3] * nm + b0.w, 0.f);
    float o4 = fmaxf(a[4] * nm + b1.x, 0.f);
    float o5 = fmaxf(a[5] * nm + b1.y, 0.f);
    float o6 = fmaxf(a[6] * nm + b1.z, 0.f);
    float o7 = fmaxf(a[7] * nm + b1.w, 0.f);
    uint4 o = make_uint4(packbf(o0, o1), packbf(o2, o3),
                         packbf(o4, o5), packbf(o6, o7));
    ((uint4*)H)[(size_t)wid * 16 + sub] = o;
  }
}

// layer-2 aggregation (R8 champion config): 8 edges x 8 lanes x uint4, 4-deep
__global__ __launch_bounds__(256) void k_agg64(const unsigned short* __restrict__ X,
                                               const int* __restrict__ csr,
                                               const int* __restrict__ offs,
                                               const int* __restrict__ cnt,
                                               const float* __restrict__ norm,
                                               const float* __restrict__ bias,
                                               unsigned short* __restrict__ H, int n) {
  int wid = blockIdx.x * 4 + (threadIdx.x >> 6);
  if (wid >= n) return;
  int lane = threadIdx.x & 63;
  int sub = lane & 7;           // 16B segment within the 128B row
  int grp = lane >> 3;          // 8 edges concurrent
  int start = offs[wid], m = cnt[wid];
  const int* p = csr + start;
  const uint4* Xv = (const uint4*)X;  // row stride 8 uint4
  float a[8] = {0.f, 0.f, 0.f, 0.f, 0.f, 0.f, 0.f, 0.f};
  for (int c0 = 0; c0 < m; c0 += 64) {
    int take = min(64, m - c0);
    int iv = p[c0 + ((lane < take) ? lane : take - 1)];
    int e = 0;
    for (; e + 32 <= take; e += 32) {
      uint4 uu[4];
#pragma unroll
      for (int j = 0; j < 4; ++j) {
        int ss = __shfl(iv, e + j * 8 + grp);
        uu[j] = Xv[(size_t)ss * 8 + sub];
      }
#pragma unroll
      for (int j = 0; j < 4; ++j) {
        a[0] += bfLo(uu[j].x); a[1] += bfHi(uu[j].x);
        a[2] += bfLo(uu[j].y); a[3] += bfHi(uu[j].y);
        a[4] += bfLo(uu[j].z); a[5] += bfHi(uu[j].z);
        a[6] += bfLo(uu[j].w); a[7] += bfHi(uu[j].w);
      }
    }
    for (; e + 8 <= take; e += 8) {
      int ss = __shfl(iv, e + grp);
      uint4 u = Xv[(size_t)ss * 8 + sub];
      a[0] += bfLo(u.x); a[1] += bfHi(u.x);
      a[2] += bfLo(u.y); a[3] += bfHi(u.y);
      a[4] += bfLo(u.z); a[5] += bfHi(u.z);
      a[6] += bfLo(u.w); a[7] += bfHi(u.w);
    }
    int r = take - e;
    if (r > 0) {
      int ss = __shfl(iv, min(e + grp, take - 1));
      uint4 u = Xv[(size_t)ss * 8 + sub];
      if (grp < r) {
        a[0] += bfLo(u.x); a[1] += bfHi(u.x);
        a[2] += bfLo(u.y); a[3] += bfHi(u.y);
        a[4] += bfLo(u.z); a[5] += bfHi(u.z);
        a[6] += bfLo(u.w); a[7] += bfHi(u.w);
      }
    }
  }
#pragma unroll
  for (int k = 0; k < 8; ++k) {
    a[k] += __shfl_xor(a[k], 8);
    a[k] += __shfl_xor(a[k], 16);
    a[k] += __shfl_xor(a[k], 32);
  }
  float nm = norm[wid];
  const float4* bv = (const float4*)bias;
  float4 b0 = bv[sub * 2], b1 = bv[sub * 2 + 1];
  if (grp == 0) {
    uint4 o = make_uint4(packbf(a[0] * nm + b0.x, a[1] * nm + b0.y),
                         packbf(a[2] * nm + b0.z, a[3] * nm + b0.w),
                         packbf(a[4] * nm + b1.x, a[5] * nm + b1.y),
                         packbf(a[6] * nm + b1.z, a[7] * nm + b1.w));
    ((uint4*)H)[(size_t)wid * 8 + sub] = o;
  }
}

// ---------------- edge scoring: 8 lanes/query, 2 queries/thread ----------------
__global__ __launch_bounds__(256) void k_score(const unsigned short* __restrict__ H,
                                               const int* __restrict__ qs,
                                               const int* __restrict__ qd,
                                               float* __restrict__ out, int q, int qStride) {
  int t = blockIdx.x * 256 + threadIdx.x;
  int sub = t & 7;
  int q0 = t >> 3;
  int q1 = q0 + qStride;
  const uint4* Hv = (const uint4*)H;   // row stride 8 uint4
  float p0 = 0.f, p1 = 0.f;
  if (q0 < q) {
    uint4 a = Hv[(size_t)qs[q0] * 8 + sub];
    uint4 b = Hv[(size_t)qd[q0] * 8 + sub];
    uint4 c, d;
    bool has1 = (q1 < q);
    if (has1) {
      c = Hv[(size_t)qs[q1] * 8 + sub];
      d = Hv[(size_t)qd[q1] * 8 + sub];
    }
    p0 = bfLo(a.x) * bfLo(b.x) + bfHi(a.x) * bfHi(b.x) +
         bfLo(a.y) * bfLo(b.y) + bfHi(a.y) * bfHi(b.y) +
         bfLo(a.z) * bfLo(b.z) + bfHi(a.z) * bfHi(b.z) +
         bfLo(a.w) * bfLo(b.w) + bfHi(a.w) * bfHi(b.w);
    if (has1)
      p1 = bfLo(c.x) * bfLo(d.x) + bfHi(c.x) * bfHi(d.x) +
           bfLo(c.y) * bfLo(d.y) + bfHi(c.y) * bfHi(d.y) +
           bfLo(c.z) * bfLo(d.z) + bfHi(c.z) * bfHi(d.z) +
           bfLo(c.w) * bfLo(d.w) + bfHi(c.w) * bfHi(d.w);
  }
  p0 += __shfl_xor(p0, 1); p1 += __shfl_xor(p1, 1);
  p0 += __shfl_xor(p0, 2); p1 += __shfl_xor(p1, 2);
  p0 += __shfl_xor(p0, 4); p1 += __shfl_xor(p1, 4);
  if (sub == 0 && q0 < q) {
    out[q0] = 1.f / (1.f + expf(-p0));
    if (q1 < q) out[q1] = 1.f / (1.f + expf(-p1));
  }
}

extern "C" void kernel_launch(void* const* d_in, const int* in_sizes, int n_in,
                              void* d_out, int out_size, void* d_ws, size_t ws_size,
                              hipStream_t stream) {
  const float* feat = (const float*)d_in[0];
  const int* esrc   = (const int*)d_in[1];
  const int* edst   = (const int*)d_in[2];
  const int* qsrc   = (const int*)d_in[3];
  const int* qdst   = (const int*)d_in[4];
  const float* W1   = (const float*)d_in[5];
  const float* b1   = (const float*)d_in[6];
  const float* W2   = (const float*)d_in[7];
  const float* b2   = (const float*)d_in[8];
  float* out = (float*)d_out;

  const int N = in_sizes[0] / 128;
  const int E = in_sizes[1];
  const int Q = in_sizes[3];

  const int G = 256;
  const int NB = (N + 255) >> 8;
  const int chunk = (E + G - 1) / G;
  const int lenS = NB * G;
  const int gScan = lenS / 256;        // == NB, blocks per half

  char* w = (char*)d_ws;
  size_t o = 0;
  unsigned short* X1 = (unsigned short*)(w + o); o += align256((size_t)N * 128 * 2);
  unsigned short* X2 = (unsigned short*)(w + o); o += align256((size_t)N * 64 * 2);
  unsigned short* H2 = (unsigned short*)(w + o); o += align256((size_t)N * 64 * 2);
  int* cntIn = (int*)(w + o);       o += align256((size_t)N * 4);
  float* normOut = (float*)(w + o); o += align256((size_t)N * 4);
  float* normIn = (float*)(w + o);  o += align256((size_t)N * 4);
  int* offs = (int*)(w + o);        o += align256((size_t)N * 4);
  int* blk = (int*)(w + o);         o += align256((size_t)lenS * 8);   // D half + S half
  int* sc = (int*)(w + o);          o += align256((size_t)lenS * 8);   // D half + S half
  int* bsums = (int*)(w + o);       o += align256((size_t)8192);
  unsigned short* W1t = (unsigned short*)(w + o); o += align256((size_t)128 * 128 * 2);
  unsigned short* W2t = (unsigned short*)(w + o); o += align256((size_t)64 * 128 * 2);
  unsigned int* pairs = (unsigned int*)(w + o); o += align256((size_t)E * 4);
  unsigned int* keys = (unsigned int*)(w + o); o += align256((size_t)E * 4);
  int* csr = (int*)(w + o);         o += align256((size_t)E * 4);

  int* blkD = blk;        int* blkS = blk + lenS;
  int* scD = sc;          int* scS = sc + lenS;

  // graph build (no global atomics); prep folded into count, scan3 folded into consumers
  k_coarse_count<<<G, 256, 0, stream>>>(esrc, edst, E, chunk, NB, G, blkD, blkS,
                                        W1, W2, W1t, W2t);
  k_scan1<<<2 * gScan, 256, 0, stream>>>(blk, sc, bsums, 2 * lenS);
  k_scan2<<<2, 512, 0, stream>>>(bsums, gScan);
  k_coarse_scatter<<<G, 256, 0, stream>>>(esrc, edst, E, chunk, NB, G, scD, scS,
                                          bsums, pairs, keys);
  k_fine<<<2 * NB, 256, 0, stream>>>(pairs, keys, scD, scS, bsums, G, E, N, NB,
                                     cntIn, normIn, offs, csr, normOut);

  const int gRows = (N + 63) / 64;
  // layer 1: X1 = (feat*normOut)@W1 ; H1 = relu(agg(X1)*normIn + b1)    [bf16]
  k_mgemm<128, float><<<gRows, 256, 0, stream>>>(feat, normOut, W1t, X1, N);
  k_agg128_relu<<<(N + 3) / 4, 256, 0, stream>>>(X1, csr, offs, cntIn, normIn, b1, X2, N);
  // layer 2: X2b = (H1*normOut)@W2 ; H2 = agg(X2b)*normIn + b2          [bf16]
  k_mgemm<64, unsigned short><<<gRows, 256, 0, stream>>>(X2, normOut, W2t, X1, N);
  k_agg64<<<(N + 3) / 4, 256, 0, stream>>>(X1, csr, offs, cntIn, normIn, b2, H2, N);
  // scoring: 2 queries per thread
  const int qHalf = (Q + 1) / 2;
  k_score<<<((qHalf * 8) + 255) / 256, 256, 0, stream>>>(H2, qsrc, qdst, out, Q, qHalf);
}

// Round 12
// 322.356 us; speedup vs baseline: 1.1595x; 1.0068x over previous
//
#include <hip/hip_runtime.h>
#include <math.h>

static inline size_t align256(size_t x) { return (x + 255) & ~(size_t)255; }

typedef __attribute__((ext_vector_type(8))) short bf16x8;
typedef __attribute__((ext_vector_type(4))) float f32x4;
typedef __attribute__((ext_vector_type(2))) float f32x2;
typedef __attribute__((ext_vector_type(2))) _Float16 half2_t;

// ---- bf16 helpers (fp32 accumulate everywhere; bf16 is storage only) ----
__device__ inline float bfLo(unsigned int u) {
  union { unsigned int i; float f; } v; v.i = u << 16; return v.f;
}
__device__ inline float bfHi(unsigned int u) {
  union { unsigned int i; float f; } v; v.i = u & 0xffff0000u; return v.f;
}
__device__ inline unsigned short f2bf(float f) {
  union { float f; unsigned int i; } v; v.f = f;
  unsigned int r = v.i + 0x7FFF + ((v.i >> 16) & 1);  // RNE
  return (unsigned short)(r >> 16);
}
__device__ inline unsigned int packbf(float lo, float hi) {
  return ((unsigned int)f2bf(hi) << 16) | f2bf(lo);
}
// f16 pack (H2 storage — finer rounding than bf16)
__device__ inline unsigned int packh(float lo, float hi) {
  union { _Float16 h[2]; unsigned int u; } v;
  v.h[0] = (_Float16)lo; v.h[1] = (_Float16)hi;
  return v.u;
}
// dot of two f16 pairs + acc: V_DOT2_F32_F16 if available, else unpack+fma
__device__ inline float qdot(unsigned int a, unsigned int b, float acc) {
#if __has_builtin(__builtin_amdgcn_fdot2)
  union { unsigned int u; half2_t h; } va, vb;
  va.u = a; vb.u = b;
  return __builtin_amdgcn_fdot2(va.h, vb.h, acc, false);
#else
  union { unsigned int u; _Float16 h[2]; } va, vb;
  va.u = a; vb.u = b;
  return acc + (float)va.h[0] * (float)vb.h[0] + (float)va.h[1] * (float)vb.h[1];
#endif
}

// ============ graph build: two-level LDS-privatized binning ============
// k_prep folded in: blocks also transpose W1/W2 to bf16 n-major.
__global__ __launch_bounds__(256) void k_coarse_count(const int* __restrict__ esrc,
                                                      const int* __restrict__ edst,
                                                      int E, int chunk, int NB, int G,
                                                      int* __restrict__ blkD,
                                                      int* __restrict__ blkS,
                                                      const float* __restrict__ W1,
                                                      const float* __restrict__ W2,
                                                      unsigned short* __restrict__ W1t,
                                                      unsigned short* __restrict__ W2t) {
  __shared__ int hD[512], hS[512];
  int blk = blockIdx.x, tid = threadIdx.x;
  int t = blk * 256 + tid;
  if (t < 128 * 128) {
    int nn = t >> 7, kk = t & 127;
    W1t[t] = f2bf(W1[kk * 128 + nn]);
  }
  if (t < 64 * 128) {
    int nn = t >> 7, kk = t & 127;
    W2t[t] = f2bf(W2[kk * 64 + nn]);
  }
  for (int i = tid; i < NB; i += 256) { hD[i] = 0; hS[i] = 0; }
  __syncthreads();
  int s0 = blk * chunk, s1 = min(E, s0 + chunk);
  for (int e = s0 + tid; e < s1; e += 256) {
    atomicAdd(&hD[edst[e] >> 8], 1);
    atomicAdd(&hS[esrc[e] >> 8], 1);
  }
  __syncthreads();
  for (int i = tid; i < NB; i += 256) {
    blkD[i * G + blk] = hD[i];
    blkS[i * G + blk] = hS[i];
  }
}

__global__ __launch_bounds__(256) void k_scan1(const int* __restrict__ in,
                                               int* __restrict__ out,
                                               int* __restrict__ bsums, int n) {
  __shared__ int s[256];
  int tid = threadIdx.x, gid = blockIdx.x * 256 + tid;
  int v = (gid < n) ? in[gid] : 0;
  s[tid] = v; __syncthreads();
  for (int o = 1; o < 256; o <<= 1) {
    int t = (tid >= o) ? s[tid - o] : 0;
    __syncthreads();
    s[tid] += t;
    __syncthreads();
  }
  if (gid < n) out[gid] = s[tid] - v;
  if (tid == 255) bsums[blockIdx.x] = s[255];
}

// grid = 2: block b scans bsums[b*nb .. b*nb+nb) independently (D half, S half)
__global__ __launch_bounds__(512) void k_scan2(int* __restrict__ bsums, int nb) {
  __shared__ int s[512];
  int tid = threadIdx.x;
  int* base = bsums + blockIdx.x * nb;
  int v = (tid < nb) ? base[tid] : 0;
  s[tid] = v; __syncthreads();
  for (int o = 1; o < 512; o <<= 1) {
    int t = (tid >= o) ? s[tid - o] : 0;
    __syncthreads();
    s[tid] += t;
    __syncthreads();
  }
  if (tid < nb) base[tid] = s[tid] - v;
}

// P3: packed scatter. pair = (src<<8)|(dst&255). scan3b folded: with G=256,
// full-scan value at sc[i*G+blk] = sc[i*G+blk] + bsums[i] (D) / bsums[NB+i] (S).
__global__ __launch_bounds__(256) void k_coarse_scatter(const int* __restrict__ esrc,
                                                        const int* __restrict__ edst,
                                                        int E, int chunk, int NB, int G,
                                                        const int* __restrict__ scD,
                                                        const int* __restrict__ scS,
                                                        const int* __restrict__ bsums,
                                                        unsigned int* __restrict__ pairs,
                                                        unsigned int* __restrict__ keys) {
  __shared__ int cD[512], cS[512];
  int blk = blockIdx.x, tid = threadIdx.x;
  for (int i = tid; i < NB; i += 256) {
    cD[i] = scD[i * G + blk] + bsums[i];
    cS[i] = scS[i * G + blk] + bsums[NB + i];
  }
  __syncthreads();
  int s0 = blk * chunk, s1 = min(E, s0 + chunk);
  for (int e = s0 + tid; e < s1; e += 256) {
    int s = esrc[e], d = edst[e];
    int pd = atomicAdd(&cD[d >> 8], 1);
    pairs[pd] = ((unsigned)s << 8) | ((unsigned)d & 255u);
    int ps = atomicAdd(&cS[s >> 8], 1);
    keys[ps] = (unsigned)s;
  }
}

// merged fine pass: blocks [0,NB) = dst buckets (csr build), [NB,2NB) = src buckets (normOut)
__global__ __launch_bounds__(256) void k_fine(const unsigned int* __restrict__ pairs,
                                              const unsigned int* __restrict__ keys,
                                              const int* __restrict__ scD,
                                              const int* __restrict__ scS,
                                              const int* __restrict__ bsums,
                                              int G, int E, int N, int NB,
                                              int* __restrict__ cntIn,
                                              float* __restrict__ normIn,
                                              int* __restrict__ offs,
                                              int* __restrict__ csr,
                                              float* __restrict__ normOut) {
  __shared__ int hist[256], scn[256], cur[256];
  int tid = threadIdx.x;
  if (blockIdx.x >= (unsigned)NB) {   // src half: degree -> normOut
    int b = blockIdx.x - NB;
    int bstart = scS[b * G] + bsums[NB + b];
    int bend = (b + 1 < NB) ? scS[(b + 1) * G] + bsums[NB + b + 1] : E;
    hist[tid] = 0;
    __syncthreads();
    for (int e = bstart + tid; e < bend; e += 256)
      atomicAdd(&hist[keys[e] & 255u], 1);
    __syncthreads();
    int node = b * 256 + tid;
    if (node < N) normOut[node] = rsqrtf((float)max(hist[tid], 1));
    return;
  }
  int b = blockIdx.x;
  int bstart = scD[b * G] + bsums[b];
  int bend = (b + 1 < NB) ? scD[(b + 1) * G] + bsums[b + 1] : E;
  hist[tid] = 0;
  __syncthreads();
  for (int e = bstart + tid; e < bend; e += 256)
    atomicAdd(&hist[pairs[e] & 255u], 1);
  __syncthreads();
  int v = hist[tid];
  scn[tid] = v;
  __syncthreads();
  for (int o = 1; o < 256; o <<= 1) {
    int t = (tid >= o) ? scn[tid - o] : 0;
    __syncthreads();
    scn[tid] += t;
    __syncthreads();
  }
  int excl = scn[tid] - v;
  cur[tid] = excl;
  int node = b * 256 + tid;
  if (node < N) {
    cntIn[node] = v;
    normIn[node] = rsqrtf((float)max(v, 1));
    offs[node] = bstart + excl;
  }
  __syncthreads();
  for (int e = bstart + tid; e < bend; e += 256) {
    unsigned int u = pairs[e];
    int p = bstart + atomicAdd(&cur[u & 255u], 1);
    csr[p] = (int)(u >> 8);
  }
}

// ---------------- MFMA GEMM: out[n x C](bf16) = diag(scale)*A[n x 128] @ W[128 x C] ----------------
template <int C, typename TA>
__global__ __launch_bounds__(256) void k_mgemm(const TA* __restrict__ A,
                                               const float* __restrict__ scale,
                                               const unsigned short* __restrict__ Wt,
                                               unsigned short* __restrict__ out, int n) {
  constexpr int KP = 136;
  constexpr int NCH = C / 16;
  __shared__ __align__(16) unsigned short Al[64 * KP];
  __shared__ __align__(16) unsigned short Wl[C * KP];
  int tid = threadIdx.x;
  int r0 = blockIdx.x * 64;

  {
    const uint4* Wg = (const uint4*)Wt;
    uint4* Wd = (uint4*)Wl;
    for (int idx = tid; idx < C * 16; idx += 256) {
      int row = idx >> 4, seg = idx & 15;
      Wd[row * 17 + seg] = Wg[idx];
    }
  }
  {
    int seg = tid & 7;
    for (int it = 0; it < 2; ++it) {
      int row = (tid >> 3) + it * 32;
      int g = r0 + row;
      float v[16];
      if (g < n) {
        float sc = scale[g];
        if constexpr (sizeof(TA) == 4) {
          const float4* Ag = (const float4*)((const float*)A + (size_t)g * 128);
#pragma unroll
          for (int j = 0; j < 4; ++j) {
            float4 f = Ag[seg * 4 + j];
            v[j * 4 + 0] = f.x * sc; v[j * 4 + 1] = f.y * sc;
            v[j * 4 + 2] = f.z * sc; v[j * 4 + 3] = f.w * sc;
          }
        } else {
          const uint4* Ag = (const uint4*)((const unsigned short*)A + (size_t)g * 128);
#pragma unroll
          for (int j = 0; j < 2; ++j) {
            uint4 u = Ag[seg * 2 + j];
            v[j * 8 + 0] = bfLo(u.x) * sc; v[j * 8 + 1] = bfHi(u.x) * sc;
            v[j * 8 + 2] = bfLo(u.y) * sc; v[j * 8 + 3] = bfHi(u.y) * sc;
            v[j * 8 + 4] = bfLo(u.z) * sc; v[j * 8 + 5] = bfHi(u.z) * sc;
            v[j * 8 + 6] = bfLo(u.w) * sc; v[j * 8 + 7] = bfHi(u.w) * sc;
          }
        }
      } else {
#pragma unroll
        for (int j = 0; j < 16; ++j) v[j] = 0.f;
      }
      uint4* dst = (uint4*)(Al + row * KP + seg * 16);
      dst[0] = make_uint4(packbf(v[0], v[1]), packbf(v[2], v[3]),
                          packbf(v[4], v[5]), packbf(v[6], v[7]));
      dst[1] = make_uint4(packbf(v[8], v[9]), packbf(v[10], v[11]),
                          packbf(v[12], v[13]), packbf(v[14], v[15]));
    }
  }
  __syncthreads();

  int lane = tid & 63;
  int w = tid >> 6;
  int quad = lane >> 4, m16 = lane & 15;
  f32x4 acc[NCH];
#pragma unroll
  for (int c = 0; c < NCH; ++c) acc[c] = (f32x4){0.f, 0.f, 0.f, 0.f};

#pragma unroll
  for (int kc = 0; kc < 4; ++kc) {
    int ko = kc * 32 + quad * 8;
    bf16x8 a = *(const bf16x8*)(Al + (w * 16 + m16) * KP + ko);
#pragma unroll
    for (int c = 0; c < NCH; ++c) {
      bf16x8 b = *(const bf16x8*)(Wl + (c * 16 + m16) * KP + ko);
      acc[c] = __builtin_amdgcn_mfma_f32_16x16x32_bf16(a, b, acc[c], 0, 0, 0);
    }
  }

#pragma unroll
  for (int c = 0; c < NCH; ++c)
#pragma unroll
    for (int r = 0; r < 4; ++r) {
      int g = r0 + w * 16 + quad * 4 + r;
      if (g < n) out[(size_t)g * C + c * 16 + m16] = f2bf(acc[c][r]);
    }
}

// ---------------- layer-1 aggregation (R8/R11 champion config) ----------------
// 4 edges x 16 lanes x uint4, 4 row-loads in flight, 32 VGPR, ~72% occupancy.
// Accumulators as f32x2 pairs so the backend can select v_pk_add_f32.
__global__ __launch_bounds__(256) void k_agg128_relu(const unsigned short* __restrict__ X,
                                                     const int* __restrict__ csr,
                                                     const int* __restrict__ offs,
                                                     const int* __restrict__ cnt,
                                                     const float* __restrict__ norm,
                                                     const float* __restrict__ bias,
                                                     unsigned short* __restrict__ H, int n) {
  int wid = blockIdx.x * 4 + (threadIdx.x >> 6);
  if (wid >= n) return;
  int lane = threadIdx.x & 63;
  int sub = lane & 15;          // 16B segment within the 256B row
  int grp = lane >> 4;          // 4 edges concurrent
  int start = offs[wid], m = cnt[wid];
  const int* p = csr + start;
  const uint4* Xv = (const uint4*)X;  // row stride 16 uint4
  f32x2 a0 = {0.f, 0.f}, a1 = {0.f, 0.f}, a2 = {0.f, 0.f}, a3 = {0.f, 0.f};
  for (int c0 = 0; c0 < m; c0 += 64) {
    int take = min(64, m - c0);
    int iv = p[c0 + ((lane < take) ? lane : take - 1)];   // one coalesced load
    int e = 0;
    for (; e + 16 <= take; e += 16) {
      uint4 uu[4];
#pragma unroll
      for (int j = 0; j < 4; ++j) {
        int ss = __shfl(iv, e + j * 4 + grp);
        uu[j] = Xv[(size_t)ss * 16 + sub];
      }
#pragma unroll
      for (int j = 0; j < 4; ++j) {
        a0 += (f32x2){bfLo(uu[j].x), bfHi(uu[j].x)};
        a1 += (f32x2){bfLo(uu[j].y), bfHi(uu[j].y)};
        a2 += (f32x2){bfLo(uu[j].z), bfHi(uu[j].z)};
        a3 += (f32x2){bfLo(uu[j].w), bfHi(uu[j].w)};
      }
    }
    for (; e + 4 <= take; e += 4) {
      int ss = __shfl(iv, e + grp);
      uint4 u = Xv[(size_t)ss * 16 + sub];
      a0 += (f32x2){bfLo(u.x), bfHi(u.x)};
      a1 += (f32x2){bfLo(u.y), bfHi(u.y)};
      a2 += (f32x2){bfLo(u.z), bfHi(u.z)};
      a3 += (f32x2){bfLo(u.w), bfHi(u.w)};
    }
    int r = take - e;
    if (r > 0) {
      int ss = __shfl(iv, min(e + grp, take - 1));
      uint4 u = Xv[(size_t)ss * 16 + sub];
      if (grp < r) {
        a0 += (f32x2){bfLo(u.x), bfHi(u.x)};
        a1 += (f32x2){bfLo(u.y), bfHi(u.y)};
        a2 += (f32x2){bfLo(u.z), bfHi(u.z)};
        a3 += (f32x2){bfLo(u.w), bfHi(u.w)};
      }
    }
  }
  float a[8] = {a0.x, a0.y, a1.x, a1.y, a2.x, a2.y, a3.x, a3.y};
#pragma unroll
  for (int k = 0; k < 8; ++k) {
    a[k] += __shfl_xor(a[k], 16);
    a[k] += __shfl_xor(a[k], 32);
  }
  float nm = norm[wid];
  const float4* bv = (const float4*)bias;     // cols sub*8 .. sub*8+7
  float4 b0 = bv[sub * 2], b1 = bv[sub * 2 + 1];
  if (grp == 0) {
    float o0 = fmaxf(a[0] * nm + b0.x, 0.f);
    float o1 = fmaxf(a[1] * nm + b0.y, 0.f);
    float o2 = fmaxf(a[2] * nm + b0.z, 0.f);
    float o3 = fmaxf(a[3] * nm + b0.w, 0.f);
    float o4 = fmaxf(a[4] * nm + b1.x, 0.f);
    float o5 = fmaxf(a[5] * nm + b1.y, 0.f);
    float o6 = fmaxf(a[6] * nm + b1.z, 0.f);
    float o7 = fmaxf(a[7] * nm + b1.w, 0.f);
    uint4 o = make_uint4(packbf(o0, o1), packbf(o2, o3),
                         packbf(o4, o5), packbf(o6, o7));
    ((uint4*)H)[(size_t)wid * 16 + sub] = o;
  }
}

// layer-2 aggregation (champion config): 8 edges x 8 lanes x uint4, 4-deep.
// Input X2b is bf16; OUTPUT H2 is f16 (finer rounding; enables fdot2 scoring).
__global__ __launch_bounds__(256) void k_agg64(const unsigned short* __restrict__ X,
                                               const int* __restrict__ csr,
                                               const int* __restrict__ offs,
                                               const int* __restrict__ cnt,
                                               const float* __restrict__ norm,
                                               const float* __restrict__ bias,
                                               unsigned short* __restrict__ H, int n) {
  int wid = blockIdx.x * 4 + (threadIdx.x >> 6);
  if (wid >= n) return;
  int lane = threadIdx.x & 63;
  int sub = lane & 7;           // 16B segment within the 128B row
  int grp = lane >> 3;          // 8 edges concurrent
  int start = offs[wid], m = cnt[wid];
  const int* p = csr + start;
  const uint4* Xv = (const uint4*)X;  // row stride 8 uint4
  f32x2 a0 = {0.f, 0.f}, a1 = {0.f, 0.f}, a2 = {0.f, 0.f}, a3 = {0.f, 0.f};
  for (int c0 = 0; c0 < m; c0 += 64) {
    int take = min(64, m - c0);
    int iv = p[c0 + ((lane < take) ? lane : take - 1)];
    int e = 0;
    for (; e + 32 <= take; e += 32) {
      uint4 uu[4];
#pragma unroll
      for (int j = 0; j < 4; ++j) {
        int ss = __shfl(iv, e + j * 8 + grp);
        uu[j] = Xv[(size_t)ss * 8 + sub];
      }
#pragma unroll
      for (int j = 0; j < 4; ++j) {
        a0 += (f32x2){bfLo(uu[j].x), bfHi(uu[j].x)};
        a1 += (f32x2){bfLo(uu[j].y), bfHi(uu[j].y)};
        a2 += (f32x2){bfLo(uu[j].z), bfHi(uu[j].z)};
        a3 += (f32x2){bfLo(uu[j].w), bfHi(uu[j].w)};
      }
    }
    for (; e + 8 <= take; e += 8) {
      int ss = __shfl(iv, e + grp);
      uint4 u = Xv[(size_t)ss * 8 + sub];
      a0 += (f32x2){bfLo(u.x), bfHi(u.x)};
      a1 += (f32x2){bfLo(u.y), bfHi(u.y)};
      a2 += (f32x2){bfLo(u.z), bfHi(u.z)};
      a3 += (f32x2){bfLo(u.w), bfHi(u.w)};
    }
    int r = take - e;
    if (r > 0) {
      int ss = __shfl(iv, min(e + grp, take - 1));
      uint4 u = Xv[(size_t)ss * 8 + sub];
      if (grp < r) {
        a0 += (f32x2){bfLo(u.x), bfHi(u.x)};
        a1 += (f32x2){bfLo(u.y), bfHi(u.y)};
        a2 += (f32x2){bfLo(u.z), bfHi(u.z)};
        a3 += (f32x2){bfLo(u.w), bfHi(u.w)};
      }
    }
  }
  float a[8] = {a0.x, a0.y, a1.x, a1.y, a2.x, a2.y, a3.x, a3.y};
#pragma unroll
  for (int k = 0; k < 8; ++k) {
    a[k] += __shfl_xor(a[k], 8);
    a[k] += __shfl_xor(a[k], 16);
    a[k] += __shfl_xor(a[k], 32);
  }
  float nm = norm[wid];
  const float4* bv = (const float4*)bias;
  float4 b0 = bv[sub * 2], b1 = bv[sub * 2 + 1];
  if (grp == 0) {
    uint4 o = make_uint4(packh(a[0] * nm + b0.x, a[1] * nm + b0.y),
                         packh(a[2] * nm + b0.z, a[3] * nm + b0.w),
                         packh(a[4] * nm + b1.x, a[5] * nm + b1.y),
                         packh(a[6] * nm + b1.z, a[7] * nm + b1.w));
    ((uint4*)H)[(size_t)wid * 8 + sub] = o;
  }
}

// ---------------- edge scoring: 8 lanes/query, 2 queries/thread, f16 fdot2 ----------------
__global__ __launch_bounds__(256) void k_score(const unsigned short* __restrict__ H,
                                               const int* __restrict__ qs,
                                               const int* __restrict__ qd,
                                               float* __restrict__ out, int q, int qStride) {
  int t = blockIdx.x * 256 + threadIdx.x;
  int sub = t & 7;
  int q0 = t >> 3;
  int q1 = q0 + qStride;
  const uint4* Hv = (const uint4*)H;   // row stride 8 uint4 (f16 pairs)
  float p0 = 0.f, p1 = 0.f;
  if (q0 < q) {
    uint4 a = Hv[(size_t)qs[q0] * 8 + sub];
    uint4 b = Hv[(size_t)qd[q0] * 8 + sub];
    uint4 c, d;
    bool has1 = (q1 < q);
    if (has1) {
      c = Hv[(size_t)qs[q1] * 8 + sub];
      d = Hv[(size_t)qd[q1] * 8 + sub];
    }
    p0 = qdot(a.x, b.x, p0); p0 = qdot(a.y, b.y, p0);
    p0 = qdot(a.z, b.z, p0); p0 = qdot(a.w, b.w, p0);
    if (has1) {
      p1 = qdot(c.x, d.x, p1); p1 = qdot(c.y, d.y, p1);
      p1 = qdot(c.z, d.z, p1); p1 = qdot(c.w, d.w, p1);
    }
  }
  p0 += __shfl_xor(p0, 1); p1 += __shfl_xor(p1, 1);
  p0 += __shfl_xor(p0, 2); p1 += __shfl_xor(p1, 2);
  p0 += __shfl_xor(p0, 4); p1 += __shfl_xor(p1, 4);
  if (sub == 0 && q0 < q) {
    out[q0] = 1.f / (1.f + expf(-p0));
    if (q1 < q) out[q1] = 1.f / (1.f + expf(-p1));
  }
}

extern "C" void kernel_launch(void* const* d_in, const int* in_sizes, int n_in,
                              void* d_out, int out_size, void* d_ws, size_t ws_size,
                              hipStream_t stream) {
  const float* feat = (const float*)d_in[0];
  const int* esrc   = (const int*)d_in[1];
  const int* edst   = (const int*)d_in[2];
  const int* qsrc   = (const int*)d_in[3];
  const int* qdst   = (const int*)d_in[4];
  const float* W1   = (const float*)d_in[5];
  const float* b1   = (const float*)d_in[6];
  const float* W2   = (const float*)d_in[7];
  const float* b2   = (const float*)d_in[8];
  float* out = (float*)d_out;

  const int N = in_sizes[0] / 128;
  const int E = in_sizes[1];
  const int Q = in_sizes[3];

  const int G = 256;
  const int NB = (N + 255) >> 8;
  const int chunk = (E + G - 1) / G;
  const int lenS = NB * G;
  const int gScan = lenS / 256;        // == NB, blocks per half

  char* w = (char*)d_ws;
  size_t o = 0;
  unsigned short* X1 = (unsigned short*)(w + o); o += align256((size_t)N * 128 * 2);
  unsigned short* X2 = (unsigned short*)(w + o); o += align256((size_t)N * 64 * 2);
  unsigned short* H2 = (unsigned short*)(w + o); o += align256((size_t)N * 64 * 2);
  int* cntIn = (int*)(w + o);       o += align256((size_t)N * 4);
  float* normOut = (float*)(w + o); o += align256((size_t)N * 4);
  float* normIn = (float*)(w + o);  o += align256((size_t)N * 4);
  int* offs = (int*)(w + o);        o += align256((size_t)N * 4);
  int* blk = (int*)(w + o);         o += align256((size_t)lenS * 8);   // D half + S half
  int* sc = (int*)(w + o);          o += align256((size_t)lenS * 8);   // D half + S half
  int* bsums = (int*)(w + o);       o += align256((size_t)8192);
  unsigned short* W1t = (unsigned short*)(w + o); o += align256((size_t)128 * 128 * 2);
  unsigned short* W2t = (unsigned short*)(w + o); o += align256((size_t)64 * 128 * 2);
  unsigned int* pairs = (unsigned int*)(w + o); o += align256((size_t)E * 4);
  unsigned int* keys = (unsigned int*)(w + o); o += align256((size_t)E * 4);
  int* csr = (int*)(w + o);         o += align256((size_t)E * 4);

  int* blkD = blk;        int* blkS = blk + lenS;
  int* scD = sc;          int* scS = sc + lenS;

  // graph build (no global atomics); prep folded into count, scan3 folded into consumers
  k_coarse_count<<<G, 256, 0, stream>>>(esrc, edst, E, chunk, NB, G, blkD, blkS,
                                        W1, W2, W1t, W2t);
  k_scan1<<<2 * gScan, 256, 0, stream>>>(blk, sc, bsums, 2 * lenS);
  k_scan2<<<2, 512, 0, stream>>>(bsums, gScan);
  k_coarse_scatter<<<G, 256, 0, stream>>>(esrc, edst, E, chunk, NB, G, scD, scS,
                                          bsums, pairs, keys);
  k_fine<<<2 * NB, 256, 0, stream>>>(pairs, keys, scD, scS, bsums, G, E, N, NB,
                                     cntIn, normIn, offs, csr, normOut);

  const int gRows = (N + 63) / 64;
  // layer 1: X1 = (feat*normOut)@W1 ; H1 = relu(agg(X1)*normIn + b1)    [bf16]
  k_mgemm<128, float><<<gRows, 256, 0, stream>>>(feat, normOut, W1t, X1, N);
  k_agg128_relu<<<(N + 3) / 4, 256, 0, stream>>>(X1, csr, offs, cntIn, normIn, b1, X2, N);
  // layer 2: X2b = (H1*normOut)@W2 ; H2 = agg(X2b)*normIn + b2          [bf16 -> f16 H2]
  k_mgemm<64, unsigned short><<<gRows, 256, 0, stream>>>(X2, normOut, W2t, X1, N);
  k_agg64<<<(N + 3) / 4, 256, 0, stream>>>(X1, csr, offs, cntIn, normIn, b2, H2, N);
  // scoring: 2 queries per thread, f16 dot2
  const int qHalf = (Q + 1) / 2;
  k_score<<<((qHalf * 8) + 255) / 256, 256, 0, stream>>>(H2, qsrc, qdst, out, Q, qHalf);
}